// Round 3
// baseline (4609.173 us; speedup 1.0000x reference)
//
#include <hip/hip_runtime.h>
#include <stdint.h>

#define NR 8192
#define DD 512
#define KB 32
#define NT (NR / KB)            // 256 tiles
#define SCALE_H 8.0f
#define ITAU 30.0f
#define PSTR 80                 // P row stride bytes (32 kv * 2B + pad)
#define TILE_B (KB * DD * 2)    // 32768 bytes per K tile
#define THR_DEF 8.0f
#define NSPLIT 4
#define TPS (NT / NSPLIT)       // 64 tiles per kv-split

typedef __bf16 bf16x8 __attribute__((ext_vector_type(8)));
typedef float f32x4 __attribute__((ext_vector_type(4)));
typedef unsigned int u32x2 __attribute__((ext_vector_type(2)));

__device__ __forceinline__ bf16x8 as_bf16x8(uint4 u) {
  union { uint4 a; bf16x8 b; } x; x.a = u; return x.b;
}
__device__ __forceinline__ unsigned short f2bf(float f) {
  unsigned u = __float_as_uint(f);
  u += 0x7FFFu + ((u >> 16) & 1u);
  return (unsigned short)(u >> 16);
}
__device__ __forceinline__ bf16x8 pack_tr(u32x2 a, u32x2 b) {
  uint4 w; w.x = a[0]; w.y = a[1]; w.z = b[0]; w.w = b[1];
  return as_bf16x8(w);
}
__device__ __forceinline__ void gload16(const void* g, void* l) {
  __builtin_amdgcn_global_load_lds((__attribute__((address_space(1))) void*)g,
                                   (__attribute__((address_space(3))) void*)l,
                                   16, 0, 0);
}

// ---------------- fp32 -> bf16 conversion ----------------
__global__ void cvt_kernel(const float* __restrict__ a, const float* __restrict__ b,
                           unsigned short* __restrict__ oa, unsigned short* __restrict__ ob) {
  const int n4 = NR * DD / 4;
  int t = blockIdx.x * blockDim.x + threadIdx.x;
  const float4* s; unsigned short* d; int i;
  if (t < n4) { s = (const float4*)a; d = oa; i = t; }
  else        { s = (const float4*)b; d = ob; i = t - n4; }
  float4 v = s[i];
  ushort4 o;
  o.x = f2bf(v.x); o.y = f2bf(v.y); o.z = f2bf(v.z); o.w = f2bf(v.w);
  *(ushort4*)(d + 4 * (size_t)i) = o;
}

__global__ void init_kernel(float* a) { if (threadIdx.x < 4) a[threadIdx.x] = 0.f; }

// ---------------- hopfield: flash attention + row normalize ----------------
// Qrows=32 per wave (2 q-groups of 16 share every K-tile LDS read -> half traffic).
// K tile LDS subtile layout [s=kv/4][t=d/16][4][16]:
//   QK^T B-frag = ds_read_b128, PV B-frag = ds_read_b64_tr_b16.
__global__ __launch_bounds__(256, 1) void hopfield_kernel(
    const unsigned short* __restrict__ imgb,
    const unsigned short* __restrict__ txtb,
    unsigned short* __restrict__ ob) {
  const int combo = blockIdx.y;
  const unsigned short* Qp = (combo == 0 || combo == 3) ? imgb : txtb;
  const unsigned short* Kp = (combo == 0 || combo == 2) ? imgb : txtb;
  unsigned short* Op = ob + (size_t)combo * NR * DD;

  __shared__ __align__(16) char smem[2 * TILE_B + 4 * 32 * PSTR];

  const int tid = threadIdx.x;
  const int lane = tid & 63;
  const int wid = tid >> 6;
  const int g = lane >> 4;
  const int c = lane & 15;
  const int qwb = blockIdx.x * 128 + wid * 32;

  // Q fragments resident: qf[qg*16+ks], A-frag row=c (q = qwb+qg*16+c), k=ks*32+g*8+i
  bf16x8 qf[32];
  #pragma unroll
  for (int qg = 0; qg < 2; ++qg)
    #pragma unroll
    for (int ks = 0; ks < 16; ++ks)
      qf[qg * 16 + ks] = as_bf16x8(*(const uint4*)(Qp + (size_t)(qwb + qg * 16 + c) * DD + ks * 32 + g * 8));

  f32x4 acc[64];                 // [qg*32 + nt]
  const f32x4 zero4 = {0.f, 0.f, 0.f, 0.f};
  #pragma unroll
  for (int i = 0; i < 64; ++i) acc[i] = zero4;
  float mr[8];
  #pragma unroll
  for (int i = 0; i < 8; ++i) mr[i] = -1e30f;

  const int poff = ((tid >> 1) & 3) * DD + (tid >> 3) * 16 + (tid & 1) * 8;
  char* lbase = smem + wid * 1024;

  const unsigned qkB = (unsigned)((c >> 2) * 4096 + (c & 3) * 32 + (g >> 1) * 128 + (g & 1) * 16);
  const unsigned trb0 = (unsigned)(2 * g) * 4096u + (unsigned)c * 8u;
  char* Pb = smem + 2 * TILE_B + wid * (32 * PSTR);

  {
    const unsigned short* gp = Kp + poff;
    #pragma unroll
    for (int q = 0; q < 8; ++q) gload16(gp + q * 4 * DD, lbase + q * 4096);
  }
  __syncthreads();

  for (int kt = 0; kt < NT; ++kt) {
    const int cur = kt & 1;
    if (kt + 1 < NT) {
      const unsigned short* gp = Kp + (size_t)(kt + 1) * KB * DD + poff;
      char* lb = lbase + (cur ^ 1) * TILE_B;
      #pragma unroll
      for (int q = 0; q < 8; ++q) gload16(gp + q * 4 * DD, lb + q * 4096);
    }
    const char* kb = smem + cur * TILE_B;

    // ---- S = Q K^T (32 q-rows x 32 kv); each B-read feeds 2 MFMA ----
    f32x4 sS[4];                 // [qg*2 + nt]
    #pragma unroll
    for (int i = 0; i < 4; ++i) sS[i] = zero4;
    __builtin_amdgcn_s_setprio(1);
    #pragma unroll
    for (int ks = 0; ks < 16; ++ks) {
      #pragma unroll
      for (int nt = 0; nt < 2; ++nt) {
        uint4 bwu = *(const uint4*)(kb + qkB + (unsigned)nt * 16384u + (unsigned)ks * 256u);
        bf16x8 bw = as_bf16x8(bwu);
        sS[nt]     = __builtin_amdgcn_mfma_f32_16x16x32_bf16(qf[ks],      bw, sS[nt],     0, 0, 0);
        sS[2 + nt] = __builtin_amdgcn_mfma_f32_16x16x32_bf16(qf[16 + ks], bw, sS[2 + nt], 0, 0, 0);
      }
    }
    __builtin_amdgcn_s_setprio(0);

    // ---- online softmax with defer-max (THR=8) ----
    float pm[8];
    bool need = false;
    #pragma unroll
    for (int qg = 0; qg < 2; ++qg) {
      #pragma unroll
      for (int r = 0; r < 4; ++r) {
        float cm = fmaxf(sS[qg * 2][r], sS[qg * 2 + 1][r]);
        cm = fmaxf(cm, __shfl_xor(cm, 1));
        cm = fmaxf(cm, __shfl_xor(cm, 2));
        cm = fmaxf(cm, __shfl_xor(cm, 4));
        cm = fmaxf(cm, __shfl_xor(cm, 8));
        pm[qg * 4 + r] = cm * SCALE_H;
        need = need || (pm[qg * 4 + r] > mr[qg * 4 + r] + THR_DEF);
      }
    }
    if (__any(need)) {
      float fac[8];
      #pragma unroll
      for (int i = 0; i < 8; ++i) {
        float mn = fmaxf(mr[i], pm[i]);
        fac[i] = __expf(mr[i] - mn);
        mr[i] = mn;
      }
      #pragma unroll
      for (int qg = 0; qg < 2; ++qg)
        #pragma unroll
        for (int nt = 0; nt < 32; ++nt) {
          acc[qg * 32 + nt][0] *= fac[qg * 4 + 0];
          acc[qg * 32 + nt][1] *= fac[qg * 4 + 1];
          acc[qg * 32 + nt][2] *= fac[qg * 4 + 2];
          acc[qg * 32 + nt][3] *= fac[qg * 4 + 3];
        }
    }
    #pragma unroll
    for (int qg = 0; qg < 2; ++qg)
      #pragma unroll
      for (int r = 0; r < 4; ++r) {
        char* pr = Pb + (qg * 16 + 4 * g + r) * PSTR;
        *(unsigned short*)(pr + c * 2)      = f2bf(__expf(sS[qg * 2][r]     * SCALE_H - mr[qg * 4 + r]));
        *(unsigned short*)(pr + 32 + c * 2) = f2bf(__expf(sS[qg * 2 + 1][r] * SCALE_H - mr[qg * 4 + r]));
      }
    bf16x8 pa0 = as_bf16x8(*(const uint4*)(Pb + (0 * 16 + c) * PSTR + g * 16));
    bf16x8 pa1 = as_bf16x8(*(const uint4*)(Pb + (1 * 16 + c) * PSTR + g * 16));

    // ---- O += P*V, depth-2 counted-lgkm pipeline; each B-frag feeds 2 MFMA ----
    asm volatile("s_waitcnt lgkmcnt(0)" ::: "memory");
    __builtin_amdgcn_sched_barrier(0);
    const unsigned trb = (unsigned)(uintptr_t)kb + trb0;
    u32x2 RA[2][4];
    #pragma unroll
    for (int pb = 0; pb < 2; ++pb) {
      unsigned ad = trb + (unsigned)(2 * pb) * 128u;
      asm volatile("ds_read_b64_tr_b16 %0, %1" : "=v"(RA[pb][0]) : "v"(ad));
      asm volatile("ds_read_b64_tr_b16 %0, %1" : "=v"(RA[pb][1]) : "v"(ad + 4096u));
      asm volatile("ds_read_b64_tr_b16 %0, %1" : "=v"(RA[pb][2]) : "v"(ad + 128u));
      asm volatile("ds_read_b64_tr_b16 %0, %1" : "=v"(RA[pb][3]) : "v"(ad + 4224u));
    }
    __builtin_amdgcn_s_setprio(1);
    #pragma unroll
    for (int np = 0; np < 16; ++np) {
      if (np < 15) { asm volatile("s_waitcnt lgkmcnt(4)" ::: "memory"); }
      else         { asm volatile("s_waitcnt lgkmcnt(0)" ::: "memory"); }
      __builtin_amdgcn_sched_barrier(0);
      const int cb = np & 1;
      bf16x8 b0 = pack_tr(RA[cb][0], RA[cb][1]);
      bf16x8 b1 = pack_tr(RA[cb][2], RA[cb][3]);
      acc[2 * np]          = __builtin_amdgcn_mfma_f32_16x16x32_bf16(pa0, b0, acc[2 * np],          0, 0, 0);
      acc[2 * np + 1]      = __builtin_amdgcn_mfma_f32_16x16x32_bf16(pa0, b1, acc[2 * np + 1],      0, 0, 0);
      acc[32 + 2 * np]     = __builtin_amdgcn_mfma_f32_16x16x32_bf16(pa1, b0, acc[32 + 2 * np],     0, 0, 0);
      acc[32 + 2 * np + 1] = __builtin_amdgcn_mfma_f32_16x16x32_bf16(pa1, b1, acc[32 + 2 * np + 1], 0, 0, 0);
      if (np < 14) {
        unsigned ad = trb + (unsigned)(2 * (np + 2)) * 128u;
        asm volatile("ds_read_b64_tr_b16 %0, %1" : "=v"(RA[cb][0]) : "v"(ad));
        asm volatile("ds_read_b64_tr_b16 %0, %1" : "=v"(RA[cb][1]) : "v"(ad + 4096u));
        asm volatile("ds_read_b64_tr_b16 %0, %1" : "=v"(RA[cb][2]) : "v"(ad + 128u));
        asm volatile("ds_read_b64_tr_b16 %0, %1" : "=v"(RA[cb][3]) : "v"(ad + 4224u));
      }
    }
    __builtin_amdgcn_s_setprio(0);
    __syncthreads();
  }

  // ---- normalize rows (softmax denom cancels) and store bf16 ----
  float rn[8];
  #pragma unroll
  for (int qg = 0; qg < 2; ++qg)
    #pragma unroll
    for (int r = 0; r < 4; ++r) {
      float s = 0.f;
      #pragma unroll
      for (int nt = 0; nt < 32; ++nt) { float v = acc[qg * 32 + nt][r]; s += v * v; }
      s += __shfl_xor(s, 1); s += __shfl_xor(s, 2);
      s += __shfl_xor(s, 4); s += __shfl_xor(s, 8);
      rn[qg * 4 + r] = rsqrtf(s);
    }
  #pragma unroll
  for (int qg = 0; qg < 2; ++qg)
    #pragma unroll
    for (int nt = 0; nt < 32; ++nt)
      #pragma unroll
      for (int r = 0; r < 4; ++r)
        Op[(size_t)(qwb + qg * 16 + 4 * g + r) * DD + nt * 16 + c] = f2bf(acc[qg * 32 + nt][r] * rn[qg * 4 + r]);
}

// ---------------- infoloob: streaming lse + diag, kv-split x4 ----------------
__global__ __launch_bounds__(256, 2) void infoloob_kernel(
    const unsigned short* __restrict__ ob, float* __restrict__ accum,
    float2* __restrict__ wsml) {
  const int pair = blockIdx.y;
  const int z = blockIdx.z;
  const unsigned short* X = ob + (size_t)pair * NR * DD;
  const unsigned short* Y = ob + (size_t)(pair + 2) * NR * DD;
  __shared__ __align__(16) char smem[2 * TILE_B];

  const int tid = threadIdx.x;
  const int lane = tid & 63;
  const int wid = tid >> 6;
  const int g = lane >> 4;
  const int c = lane & 15;
  const int rowb = blockIdx.x * 64 + wid * 16;

  bf16x8 qf[16];
  #pragma unroll
  for (int ks = 0; ks < 16; ++ks)
    qf[ks] = as_bf16x8(*(const uint4*)(X + (size_t)(rowb + c) * DD + ks * 32 + g * 8));

  float mr[4] = {-1e30f, -1e30f, -1e30f, -1e30f};
  float lr[4] = {0.f, 0.f, 0.f, 0.f};
  float dacc = 0.f;
  const f32x4 zero4 = {0.f, 0.f, 0.f, 0.f};

  const int poff = ((tid >> 1) & 3) * DD + (tid >> 3) * 16 + (tid & 1) * 8;
  char* lbase = smem + wid * 1024;
  const unsigned qkB = (unsigned)((c >> 2) * 4096 + (c & 3) * 32 + (g >> 1) * 128 + (g & 1) * 16);
  const int kt0 = z * TPS;

  {
    const unsigned short* gp = Y + (size_t)kt0 * KB * DD + poff;
    #pragma unroll
    for (int q = 0; q < 8; ++q) gload16(gp + q * 4 * DD, lbase + q * 4096);
  }
  __syncthreads();

  for (int kk = 0; kk < TPS; ++kk) {
    const int kt = kt0 + kk;
    const int cur = kk & 1;
    if (kk + 1 < TPS) {
      const unsigned short* gp = Y + (size_t)(kt + 1) * KB * DD + poff;
      char* lb = lbase + (cur ^ 1) * TILE_B;
      #pragma unroll
      for (int q = 0; q < 8; ++q) gload16(gp + q * 4 * DD, lb + q * 4096);
    }
    const char* kb = smem + cur * TILE_B;

    f32x4 sS[2] = {zero4, zero4};
    __builtin_amdgcn_s_setprio(1);
    #pragma unroll
    for (int ks = 0; ks < 16; ++ks) {
      #pragma unroll
      for (int nt = 0; nt < 2; ++nt) {
        uint4 bw = *(const uint4*)(kb + qkB + (unsigned)nt * 16384u + (unsigned)ks * 256u);
        sS[nt] = __builtin_amdgcn_mfma_f32_16x16x32_bf16(qf[ks], as_bf16x8(bw), sS[nt], 0, 0, 0);
      }
    }
    __builtin_amdgcn_s_setprio(0);

    const bool hd = (kt == (rowb >> 5));
    #pragma unroll
    for (int r = 0; r < 4; ++r) {
      float a0 = sS[0][r] * ITAU, a1 = sS[1][r] * ITAU;
      if (hd) {
        const int ig = rowb + 4 * g + r;
        if (kt * KB + c == ig)      { dacc += a0; a0 = -1e30f; }
        if (kt * KB + 16 + c == ig) { dacc += a1; a1 = -1e30f; }
      }
      float cm = fmaxf(a0, a1);
      cm = fmaxf(cm, __shfl_xor(cm, 1));
      cm = fmaxf(cm, __shfl_xor(cm, 2));
      cm = fmaxf(cm, __shfl_xor(cm, 4));
      cm = fmaxf(cm, __shfl_xor(cm, 8));
      float mn = fmaxf(mr[r], cm);
      float f = __expf(mr[r] - mn);
      float ps = __expf(a0 - mn) + __expf(a1 - mn);
      ps += __shfl_xor(ps, 1); ps += __shfl_xor(ps, 2);
      ps += __shfl_xor(ps, 4); ps += __shfl_xor(ps, 8);
      lr[r] = lr[r] * f + ps;
      mr[r] = mn;
    }
    __syncthreads();
  }

  // per-row (m,l) partials for this kv-split
  if (c == 0) {
    #pragma unroll
    for (int r = 0; r < 4; ++r)
      wsml[(size_t)(pair * NSPLIT + z) * NR + rowb + 4 * g + r] = make_float2(mr[r], lr[r]);
  }
  float ds = dacc;
  ds += __shfl_xor(ds, 1);  ds += __shfl_xor(ds, 2);  ds += __shfl_xor(ds, 4);
  ds += __shfl_xor(ds, 8);  ds += __shfl_xor(ds, 16); ds += __shfl_xor(ds, 32);
  if (lane == 0) atomicAdd(&accum[2 * pair + 1], ds);
}

// merge kv-split lse partials, sum over rows
__global__ void lse_merge_kernel(const float2* __restrict__ wsml, float* __restrict__ accum) {
  const int pair = blockIdx.y;
  const int row = blockIdx.x * 256 + threadIdx.x;
  float2 v[NSPLIT];
  float M = -1e30f;
  #pragma unroll
  for (int z = 0; z < NSPLIT; ++z) {
    v[z] = wsml[(size_t)(pair * NSPLIT + z) * NR + row];
    M = fmaxf(M, v[z].x);
  }
  float l = 0.f;
  #pragma unroll
  for (int z = 0; z < NSPLIT; ++z) l += v[z].y * __expf(v[z].x - M);
  float lse = M + __logf(l);
  lse += __shfl_xor(lse, 1);  lse += __shfl_xor(lse, 2);  lse += __shfl_xor(lse, 4);
  lse += __shfl_xor(lse, 8);  lse += __shfl_xor(lse, 16); lse += __shfl_xor(lse, 32);
  if ((threadIdx.x & 63) == 0) atomicAdd(&accum[2 * pair], lse);
}

__global__ void final_kernel(const float* a, float* o) {
  if (threadIdx.x == 0)
    o[0] = 0.5f * ((a[0] - a[1]) + (a[2] - a[3])) / (float)NR;
}

extern "C" void kernel_launch(void* const* d_in, const int* in_sizes, int n_in,
                              void* d_out, int out_size, void* d_ws, size_t ws_size,
                              hipStream_t stream) {
  (void)in_sizes; (void)n_in; (void)out_size; (void)ws_size;
  const float* img = (const float*)d_in[0];
  const float* txt = (const float*)d_in[1];
  const size_t ND = (size_t)NR * DD;
  unsigned short* imgb = (unsigned short*)d_ws;
  unsigned short* txtb = imgb + ND;
  unsigned short* ob   = txtb + ND;               // 4 x [N,D] bf16 outputs
  float* accum = (float*)(ob + 4 * ND);           // 4 f32 partial sums
  float2* wsml = (float2*)(accum + 4);            // 2*NSPLIT*NR float2 lse partials

  cvt_kernel<<<dim3(2 * (NR * DD / 4) / 256), dim3(256), 0, stream>>>(img, txt, imgb, txtb);
  init_kernel<<<dim3(1), dim3(64), 0, stream>>>(accum);
  hopfield_kernel<<<dim3(NR / 128, 4), dim3(256), 0, stream>>>(imgb, txtb, ob);
  infoloob_kernel<<<dim3(NR / 64, 2, NSPLIT), dim3(256), 0, stream>>>(ob, accum, wsml);
  lse_merge_kernel<<<dim3(NR / 256, 2), dim3(256), 0, stream>>>(wsml, accum);
  final_kernel<<<dim3(1), dim3(64), 0, stream>>>(accum, (float*)d_out);
}

// Round 4
// 1087.863 us; speedup vs baseline: 4.2369x; 4.2369x over previous
//
#include <hip/hip_runtime.h>
#include <stdint.h>

#define NR 8192
#define DD 512
#define KB 32
#define NT (NR / KB)            // 256 tiles
#define SCALE_H 8.0f
#define ITAU 30.0f
#define PSTR 80                 // P row stride bytes (32 kv * 2B + pad)
#define SBS 4112                // s-block stride: 4096+16 -> bank phase rotates 16B/s-block
#define TILE_B 32896            // tile buffer footprint (7*4112+4096 = 32880, padded)
#define THR_DEF 8.0f
#define NSPLIT 4
#define TPS (NT / NSPLIT)       // 64 tiles per kv-split
#define ITILE_B (KB * DD * 2)   // infoloob tile (32768, linear 4096-stride layout)

typedef __bf16 bf16x8 __attribute__((ext_vector_type(8)));
typedef float f32x4 __attribute__((ext_vector_type(4)));
typedef unsigned int u32x2 __attribute__((ext_vector_type(2)));

__device__ __forceinline__ bf16x8 as_bf16x8(uint4 u) {
  union { uint4 a; bf16x8 b; } x; x.a = u; return x.b;
}
__device__ __forceinline__ unsigned short f2bf(float f) {
  unsigned u = __float_as_uint(f);
  u += 0x7FFFu + ((u >> 16) & 1u);
  return (unsigned short)(u >> 16);
}
__device__ __forceinline__ bf16x8 pack_tr(u32x2 a, u32x2 b) {
  uint4 w; w.x = a[0]; w.y = a[1]; w.z = b[0]; w.w = b[1];
  return as_bf16x8(w);
}
__device__ __forceinline__ void gload16(const void* g, void* l) {
  __builtin_amdgcn_global_load_lds((__attribute__((address_space(1))) void*)g,
                                   (__attribute__((address_space(3))) void*)l,
                                   16, 0, 0);
}

// ---------------- fp32 -> bf16 conversion ----------------
__global__ void cvt_kernel(const float* __restrict__ a, const float* __restrict__ b,
                           unsigned short* __restrict__ oa, unsigned short* __restrict__ ob) {
  const int n4 = NR * DD / 4;
  int t = blockIdx.x * blockDim.x + threadIdx.x;
  const float4* s; unsigned short* d; int i;
  if (t < n4) { s = (const float4*)a; d = oa; i = t; }
  else        { s = (const float4*)b; d = ob; i = t - n4; }
  float4 v = s[i];
  ushort4 o;
  o.x = f2bf(v.x); o.y = f2bf(v.y); o.z = f2bf(v.z); o.w = f2bf(v.w);
  *(ushort4*)(d + 4 * (size_t)i) = o;
}

__global__ void init_kernel(float* a) { if (threadIdx.x < 4) a[threadIdx.x] = 0.f; }

// ---------------- hopfield: flash attention + row normalize ----------------
// Qrows=16/wave (round-2 structure; Qrows=32 spills — r3 post-mortem).
// K tile LDS subtile layout [s=kv/4][t=d/16][4][16], s-block stride SBS=4112
// so the 4 lane-groups of each ds_read_b64_tr_b16 hit bank phases 0/32/64/96.
__global__ __launch_bounds__(256, 2) void hopfield_kernel(
    const unsigned short* __restrict__ imgb,
    const unsigned short* __restrict__ txtb,
    unsigned short* __restrict__ ob) {
  const int combo = blockIdx.y;
  const unsigned short* Qp = (combo == 0 || combo == 3) ? imgb : txtb;
  const unsigned short* Kp = (combo == 0 || combo == 2) ? imgb : txtb;
  unsigned short* Op = ob + (size_t)combo * NR * DD;

  __shared__ __align__(16) char smem[2 * TILE_B + 4 * 16 * PSTR];

  const int tid = threadIdx.x;
  const int lane = tid & 63;
  const int wid = tid >> 6;
  const int g = lane >> 4;
  const int c = lane & 15;
  const int qwb = blockIdx.x * 64 + wid * 16;

  // Q fragments in registers for the whole kernel (A-frag: row=c, k=ks*32+8g+i)
  bf16x8 qf[16];
  #pragma unroll
  for (int ks = 0; ks < 16; ++ks)
    qf[ks] = as_bf16x8(*(const uint4*)(Qp + (size_t)(qwb + c) * DD + ks * 32 + g * 8));

  f32x4 acc[32];
  const f32x4 zero4 = {0.f, 0.f, 0.f, 0.f};
  #pragma unroll
  for (int i = 0; i < 32; ++i) acc[i] = zero4;
  float mr[4] = {-1e30f, -1e30f, -1e30f, -1e30f};

  // staging: issue q = s-block; within block lane-linear 16B chunks
  const int poff = ((tid >> 1) & 3) * DD + (tid >> 3) * 16 + (tid & 1) * 8;
  char* lbase = smem + wid * 1024;

  const unsigned qkB = (unsigned)((c >> 2) * SBS + (c & 3) * 32 + (g >> 1) * 128 + (g & 1) * 16);
  const unsigned trb0 = (unsigned)(2 * g) * (unsigned)SBS + (unsigned)c * 8u;
  char* Pb = smem + 2 * TILE_B + wid * (16 * PSTR);

  // prologue: stage tile 0 into buf 0
  {
    const unsigned short* gp = Kp + poff;
    #pragma unroll
    for (int q = 0; q < 8; ++q) gload16(gp + q * 4 * DD, lbase + q * SBS);
  }
  __syncthreads();

  for (int kt = 0; kt < NT; ++kt) {
    const int cur = kt & 1;
    if (kt + 1 < NT) {
      const unsigned short* gp = Kp + (size_t)(kt + 1) * KB * DD + poff;
      char* lb = lbase + (cur ^ 1) * TILE_B;
      #pragma unroll
      for (int q = 0; q < 8; ++q) gload16(gp + q * 4 * DD, lb + q * SBS);
    }
    const char* kb = smem + cur * TILE_B;

    // ---- S = Q K^T (16 q-rows x 32 kv) ----
    f32x4 sS[2] = {zero4, zero4};
    __builtin_amdgcn_s_setprio(1);
    #pragma unroll
    for (int ks = 0; ks < 16; ++ks) {
      #pragma unroll
      for (int nt = 0; nt < 2; ++nt) {
        uint4 bw = *(const uint4*)(kb + qkB + (unsigned)nt * (4u * SBS) + (unsigned)ks * 256u);
        sS[nt] = __builtin_amdgcn_mfma_f32_16x16x32_bf16(qf[ks], as_bf16x8(bw), sS[nt], 0, 0, 0);
      }
    }
    __builtin_amdgcn_s_setprio(0);

    // ---- online softmax, defer-max (THR=8) ----
    float pm[4];
    bool need = false;
    #pragma unroll
    for (int r = 0; r < 4; ++r) {
      float cm = fmaxf(sS[0][r], sS[1][r]);
      cm = fmaxf(cm, __shfl_xor(cm, 1));
      cm = fmaxf(cm, __shfl_xor(cm, 2));
      cm = fmaxf(cm, __shfl_xor(cm, 4));
      cm = fmaxf(cm, __shfl_xor(cm, 8));
      pm[r] = cm * SCALE_H;
      need = need || (pm[r] > mr[r] + THR_DEF);
    }
    if (__any(need)) {
      float fac[4];
      #pragma unroll
      for (int r = 0; r < 4; ++r) {
        float mn = fmaxf(mr[r], pm[r]);
        fac[r] = __expf(mr[r] - mn);
        mr[r] = mn;
      }
      #pragma unroll
      for (int nt = 0; nt < 32; ++nt) {
        acc[nt][0] *= fac[0]; acc[nt][1] *= fac[1];
        acc[nt][2] *= fac[2]; acc[nt][3] *= fac[3];
      }
    }
    #pragma unroll
    for (int r = 0; r < 4; ++r) {
      *(unsigned short*)(Pb + (4 * g + r) * PSTR + c * 2)      = f2bf(__expf(sS[0][r] * SCALE_H - mr[r]));
      *(unsigned short*)(Pb + (4 * g + r) * PSTR + 32 + c * 2) = f2bf(__expf(sS[1][r] * SCALE_H - mr[r]));
    }
    bf16x8 pa0 = as_bf16x8(*(const uint4*)(Pb + c * PSTR + g * 16));

    // ---- O += P*V, depth-2 counted-lgkm pipeline over 16 d-column pairs ----
    asm volatile("s_waitcnt lgkmcnt(0)" ::: "memory");
    __builtin_amdgcn_sched_barrier(0);
    const unsigned trb = (unsigned)(uintptr_t)kb + trb0;
    u32x2 RA[2][4];
    #pragma unroll
    for (int pb = 0; pb < 2; ++pb) {
      unsigned ad = trb + (unsigned)(2 * pb) * 128u;
      asm volatile("ds_read_b64_tr_b16 %0, %1" : "=v"(RA[pb][0]) : "v"(ad));
      asm volatile("ds_read_b64_tr_b16 %0, %1" : "=v"(RA[pb][1]) : "v"(ad + (unsigned)SBS));
      asm volatile("ds_read_b64_tr_b16 %0, %1" : "=v"(RA[pb][2]) : "v"(ad + 128u));
      asm volatile("ds_read_b64_tr_b16 %0, %1" : "=v"(RA[pb][3]) : "v"(ad + (unsigned)SBS + 128u));
    }
    __builtin_amdgcn_s_setprio(1);
    #pragma unroll
    for (int np = 0; np < 16; ++np) {
      if (np < 15) { asm volatile("s_waitcnt lgkmcnt(4)" ::: "memory"); }
      else         { asm volatile("s_waitcnt lgkmcnt(0)" ::: "memory"); }
      __builtin_amdgcn_sched_barrier(0);
      const int cb = np & 1;
      acc[2 * np]     = __builtin_amdgcn_mfma_f32_16x16x32_bf16(pa0, pack_tr(RA[cb][0], RA[cb][1]), acc[2 * np],     0, 0, 0);
      acc[2 * np + 1] = __builtin_amdgcn_mfma_f32_16x16x32_bf16(pa0, pack_tr(RA[cb][2], RA[cb][3]), acc[2 * np + 1], 0, 0, 0);
      if (np < 14) {
        unsigned ad = trb + (unsigned)(2 * (np + 2)) * 128u;
        asm volatile("ds_read_b64_tr_b16 %0, %1" : "=v"(RA[cb][0]) : "v"(ad));
        asm volatile("ds_read_b64_tr_b16 %0, %1" : "=v"(RA[cb][1]) : "v"(ad + (unsigned)SBS));
        asm volatile("ds_read_b64_tr_b16 %0, %1" : "=v"(RA[cb][2]) : "v"(ad + 128u));
        asm volatile("ds_read_b64_tr_b16 %0, %1" : "=v"(RA[cb][3]) : "v"(ad + (unsigned)SBS + 128u));
      }
    }
    __builtin_amdgcn_s_setprio(0);
    __syncthreads();   // drains vmcnt(0): next tile's staging complete
  }

  // ---- normalize rows (softmax denom cancels) and store bf16 ----
  float rn[4];
  #pragma unroll
  for (int r = 0; r < 4; ++r) {
    float s = 0.f;
    #pragma unroll
    for (int nt = 0; nt < 32; ++nt) { float v = acc[nt][r]; s += v * v; }
    s += __shfl_xor(s, 1); s += __shfl_xor(s, 2);
    s += __shfl_xor(s, 4); s += __shfl_xor(s, 8);
    rn[r] = rsqrtf(s);
  }
  #pragma unroll
  for (int nt = 0; nt < 32; ++nt) {
    #pragma unroll
    for (int r = 0; r < 4; ++r)
      Op[(size_t)(qwb + 4 * g + r) * DD + nt * 16 + c] = f2bf(acc[nt][r] * rn[r]);
  }
}

// ---------------- infoloob: streaming lse + diag, kv-split x4 ----------------
__global__ __launch_bounds__(256, 2) void infoloob_kernel(
    const unsigned short* __restrict__ ob, float* __restrict__ accum,
    float2* __restrict__ wsml) {
  const int pair = blockIdx.y;
  const int z = blockIdx.z;
  const unsigned short* X = ob + (size_t)pair * NR * DD;
  const unsigned short* Y = ob + (size_t)(pair + 2) * NR * DD;
  __shared__ __align__(16) char smem[2 * ITILE_B];

  const int tid = threadIdx.x;
  const int lane = tid & 63;
  const int wid = tid >> 6;
  const int g = lane >> 4;
  const int c = lane & 15;
  const int rowb = blockIdx.x * 64 + wid * 16;

  bf16x8 qf[16];
  #pragma unroll
  for (int ks = 0; ks < 16; ++ks)
    qf[ks] = as_bf16x8(*(const uint4*)(X + (size_t)(rowb + c) * DD + ks * 32 + g * 8));

  float mr[4] = {-1e30f, -1e30f, -1e30f, -1e30f};
  float lr[4] = {0.f, 0.f, 0.f, 0.f};
  float dacc = 0.f;
  const f32x4 zero4 = {0.f, 0.f, 0.f, 0.f};

  const int poff = ((tid >> 1) & 3) * DD + (tid >> 3) * 16 + (tid & 1) * 8;
  char* lbase = smem + wid * 1024;
  const unsigned qkB = (unsigned)((c >> 2) * 4096 + (c & 3) * 32 + (g >> 1) * 128 + (g & 1) * 16);
  const int kt0 = z * TPS;

  {
    const unsigned short* gp = Y + (size_t)kt0 * KB * DD + poff;
    #pragma unroll
    for (int q = 0; q < 8; ++q) gload16(gp + q * 4 * DD, lbase + q * 4096);
  }
  __syncthreads();

  for (int kk = 0; kk < TPS; ++kk) {
    const int kt = kt0 + kk;
    const int cur = kk & 1;
    if (kk + 1 < TPS) {
      const unsigned short* gp = Y + (size_t)(kt + 1) * KB * DD + poff;
      char* lb = lbase + (cur ^ 1) * ITILE_B;
      #pragma unroll
      for (int q = 0; q < 8; ++q) gload16(gp + q * 4 * DD, lb + q * 4096);
    }
    const char* kb = smem + cur * ITILE_B;

    f32x4 sS[2] = {zero4, zero4};
    __builtin_amdgcn_s_setprio(1);
    #pragma unroll
    for (int ks = 0; ks < 16; ++ks) {
      #pragma unroll
      for (int nt = 0; nt < 2; ++nt) {
        uint4 bw = *(const uint4*)(kb + qkB + (unsigned)nt * 16384u + (unsigned)ks * 256u);
        sS[nt] = __builtin_amdgcn_mfma_f32_16x16x32_bf16(qf[ks], as_bf16x8(bw), sS[nt], 0, 0, 0);
      }
    }
    __builtin_amdgcn_s_setprio(0);

    const bool hd = (kt == (rowb >> 5));
    #pragma unroll
    for (int r = 0; r < 4; ++r) {
      float a0 = sS[0][r] * ITAU, a1 = sS[1][r] * ITAU;
      if (hd) {
        const int ig = rowb + 4 * g + r;
        if (kt * KB + c == ig)      { dacc += a0; a0 = -1e30f; }
        if (kt * KB + 16 + c == ig) { dacc += a1; a1 = -1e30f; }
      }
      float cm = fmaxf(a0, a1);
      cm = fmaxf(cm, __shfl_xor(cm, 1));
      cm = fmaxf(cm, __shfl_xor(cm, 2));
      cm = fmaxf(cm, __shfl_xor(cm, 4));
      cm = fmaxf(cm, __shfl_xor(cm, 8));
      float mn = fmaxf(mr[r], cm);
      float f = __expf(mr[r] - mn);
      float ps = __expf(a0 - mn) + __expf(a1 - mn);
      ps += __shfl_xor(ps, 1); ps += __shfl_xor(ps, 2);
      ps += __shfl_xor(ps, 4); ps += __shfl_xor(ps, 8);
      lr[r] = lr[r] * f + ps;
      mr[r] = mn;
    }
    __syncthreads();
  }

  if (c == 0) {
    #pragma unroll
    for (int r = 0; r < 4; ++r)
      wsml[(size_t)(pair * NSPLIT + z) * NR + rowb + 4 * g + r] = make_float2(mr[r], lr[r]);
  }
  float ds = dacc;
  ds += __shfl_xor(ds, 1);  ds += __shfl_xor(ds, 2);  ds += __shfl_xor(ds, 4);
  ds += __shfl_xor(ds, 8);  ds += __shfl_xor(ds, 16); ds += __shfl_xor(ds, 32);
  if (lane == 0) atomicAdd(&accum[2 * pair + 1], ds);
}

// merge kv-split lse partials, sum over rows
__global__ void lse_merge_kernel(const float2* __restrict__ wsml, float* __restrict__ accum) {
  const int pair = blockIdx.y;
  const int row = blockIdx.x * 256 + threadIdx.x;
  float2 v[NSPLIT];
  float M = -1e30f;
  #pragma unroll
  for (int z = 0; z < NSPLIT; ++z) {
    v[z] = wsml[(size_t)(pair * NSPLIT + z) * NR + row];
    M = fmaxf(M, v[z].x);
  }
  float l = 0.f;
  #pragma unroll
  for (int z = 0; z < NSPLIT; ++z) l += v[z].y * __expf(v[z].x - M);
  float lse = M + __logf(l);
  lse += __shfl_xor(lse, 1);  lse += __shfl_xor(lse, 2);  lse += __shfl_xor(lse, 4);
  lse += __shfl_xor(lse, 8);  lse += __shfl_xor(lse, 16); lse += __shfl_xor(lse, 32);
  if ((threadIdx.x & 63) == 0) atomicAdd(&accum[2 * pair], lse);
}

__global__ void final_kernel(const float* a, float* o) {
  if (threadIdx.x == 0)
    o[0] = 0.5f * ((a[0] - a[1]) + (a[2] - a[3])) / (float)NR;
}

extern "C" void kernel_launch(void* const* d_in, const int* in_sizes, int n_in,
                              void* d_out, int out_size, void* d_ws, size_t ws_size,
                              hipStream_t stream) {
  (void)in_sizes; (void)n_in; (void)out_size; (void)ws_size;
  const float* img = (const float*)d_in[0];
  const float* txt = (const float*)d_in[1];
  const size_t ND = (size_t)NR * DD;
  unsigned short* imgb = (unsigned short*)d_ws;
  unsigned short* txtb = imgb + ND;
  unsigned short* ob   = txtb + ND;               // 4 x [N,D] bf16 outputs
  float* accum = (float*)(ob + 4 * ND);           // 4 f32 partial sums
  float2* wsml = (float2*)(accum + 4);            // 2*NSPLIT*NR float2 lse partials

  cvt_kernel<<<dim3(2 * (NR * DD / 4) / 256), dim3(256), 0, stream>>>(img, txt, imgb, txtb);
  init_kernel<<<dim3(1), dim3(64), 0, stream>>>(accum);
  hopfield_kernel<<<dim3(NR / 64, 4), dim3(256), 0, stream>>>(imgb, txtb, ob);
  infoloob_kernel<<<dim3(NR / 64, 2, NSPLIT), dim3(256), 0, stream>>>(ob, accum, wsml);
  lse_merge_kernel<<<dim3(NR / 256, 2), dim3(256), 0, stream>>>(wsml, accum);
  final_kernel<<<dim3(1), dim3(64), 0, stream>>>(accum, (float*)d_out);
}